// Round 3
// baseline (537.033 us; speedup 1.0000x reference)
//
#include <hip/hip_runtime.h>
#include <hip/hip_bf16.h>
#include <stdint.h>

// ---------------------------------------------------------------------------
// JointEmbeddingClassifier on MI355X (gfx950) — R3: single persistent kernel.
// R2 post-mortem: gemm1 = 91us but total = 324us -> ~230us of inter-dispatch
// overhead across 6 kernel nodes. R3 fuses everything into one 512-block
// persistent kernel with device-scope grid barriers (512 = 256 CU x 2
// blocks/CU guaranteed by __launch_bounds__(256,2)).
//   P0: cast x->bf16, transpose Wp|Ws, pack child/parent weights, bucket y
//   P1: gemm1 [4096,4096]x[4096,2048] (68.7 GFLOP, m97-style 128^2 tile)
//   P2: grouped head gemm (child experts per class + parent logits)
// ---------------------------------------------------------------------------

typedef __attribute__((ext_vector_type(4))) float  floatx4;
typedef __attribute__((ext_vector_type(8))) short  shortx8;
typedef __attribute__((ext_vector_type(4))) short  shortx4;
typedef __attribute__((ext_vector_type(8))) __bf16 bf16x8;

#define GRID 512
#define BM 128
#define BN 128
#define BK 64

static __device__ __forceinline__ ushort f32_to_bf16_rne(float f) {
  uint32_t u = __builtin_bit_cast(uint32_t, f);
  u += 0x7FFFu + ((u >> 16) & 1u);      // RNE (no NaN inputs here)
  return (ushort)(u >> 16);
}

// async global->LDS, 16B per lane. LDS dest = wave-uniform base + lane*16;
// global address may be fully per-lane (used for perm-indirected rows).
static __device__ __forceinline__ void async_copy16(const void* g, void* lds) {
  __builtin_amdgcn_global_load_lds(
      (__attribute__((address_space(1))) void*)(uintptr_t)g,
      (__attribute__((address_space(3))) void*)(uintptr_t)lds,
      16, 0, 0);
}

// device-scope grid barrier; all GRID blocks are co-resident by construction.
static __device__ __forceinline__ void grid_barrier(int* bar, int id) {
  __syncthreads();
  if (threadIdx.x == 0) {
    __threadfence();  // release: drain stores, make visible across XCDs
    __hip_atomic_fetch_add(&bar[id], 1, __ATOMIC_ACQ_REL, __HIP_MEMORY_SCOPE_AGENT);
    int guard = 0;
    while (__hip_atomic_load(&bar[id], __ATOMIC_ACQUIRE, __HIP_MEMORY_SCOPE_AGENT) < GRID) {
      __builtin_amdgcn_s_sleep(2);
      if (++guard > 200000000) break;   // fail loud rather than hang forever
    }
  }
  __syncthreads();
  __threadfence();    // acquire side for all threads (invalidate stale L1)
}

// MFMA compute on one staged BKx(128|128) LDS tile pair (XOR-swizzled rows).
static __device__ __forceinline__ void mfma_bk_step(
    const ushort* lA, const ushort* lB, floatx4 acc[4][4],
    int wr, int wc, int r16, int quad)
{
  #pragma unroll
  for (int ks = 0; ks < 2; ++ks) {
    bf16x8 af[4], bfv[4];
    const int pc = (((ks * 4) + quad) ^ (r16 & 7)) * 8;
    #pragma unroll
    for (int mi = 0; mi < 4; ++mi) {
      const int row = wr * 64 + mi * 16 + r16;
      af[mi] = *reinterpret_cast<const bf16x8*>(lA + row * BK + pc);
    }
    #pragma unroll
    for (int ni = 0; ni < 4; ++ni) {
      const int row = wc * 64 + ni * 16 + r16;
      bfv[ni] = *reinterpret_cast<const bf16x8*>(lB + row * BK + pc);
    }
    #pragma unroll
    for (int mi = 0; mi < 4; ++mi)
      #pragma unroll
      for (int ni = 0; ni < 4; ++ni)
        acc[mi][ni] = __builtin_amdgcn_mfma_f32_16x16x32_bf16(
            af[mi], bfv[ni], acc[mi][ni], 0, 0, 0);
  }
}

// C[mTile*128.., nTile*128..] += A[m,:K] . B[n,:K]^T  (operands [rows][K] bf16)
static __device__ __forceinline__ void gemm_core_128(
    const ushort* __restrict__ A, const ushort* __restrict__ B,
    int lda, int ldb, int K, int mTile, int nTile,
    ushort* lA, ushort* lB, floatx4 acc[4][4])
{
  const int t    = threadIdx.x;
  const int w    = t >> 6;
  const int lane = t & 63;
  const int wr   = w >> 1;
  const int wc   = w & 1;
  const int r16  = lane & 15;
  const int quad = lane >> 4;
  const int sr   = lane >> 3;
  const int sc   = lane & 7;

  const ushort* Abase = A + (size_t)(mTile * BM) * lda;
  const ushort* Bbase = B + (size_t)(nTile * BN) * ldb;

  for (int k0 = 0; k0 < K; k0 += BK) {
    #pragma unroll
    for (int c2 = 0; c2 < 4; ++c2) {
      const int r  = 32 * w + 8 * c2 + sr;
      const int gc = sc ^ sr;
      async_copy16(Abase + (size_t)r * lda + k0 + gc * 8, lA + (32 * w + 8 * c2) * BK);
      async_copy16(Bbase + (size_t)r * ldb + k0 + gc * 8, lB + (32 * w + 8 * c2) * BK);
    }
    __syncthreads();
    mfma_bk_step(lA, lB, acc, wr, wc, r16, quad);
    __syncthreads();
  }
}

// ---------------------------------------------------------------------------

__global__ __launch_bounds__(256, 2) void k_mega(
    const float* __restrict__ x,   const int* __restrict__ y,
    const float* __restrict__ Wp,  const float* __restrict__ bp,
    const float* __restrict__ Ws,  const float* __restrict__ bs,
    const float* __restrict__ Wc,  const float* __restrict__ bc,
    const float* __restrict__ cw0, const float* __restrict__ cb0,
    const float* __restrict__ cw1, const float* __restrict__ cb1,
    ushort* __restrict__ xb,  ushort* __restrict__ Bt1,
    ushort* __restrict__ Pb,  ushort* __restrict__ Sb,
    ushort* __restrict__ cwb, ushort* __restrict__ Wcb,
    int* __restrict__ perm, int* __restrict__ offs, int* bar,
    float* __restrict__ P, float* __restrict__ S,
    float* __restrict__ outParent, float* __restrict__ out0, float* __restrict__ out1)
{
  __shared__ __align__(16) ushort lA[BM * BK];
  __shared__ __align__(16) ushort lB[BN * BK];
  __shared__ int hist[32], hbase[32], hcur[32];

  const int b = blockIdx.x;
  const int t = threadIdx.x;

  // ====================== P0: prep ======================
  // (a) cast x [4096*4096] f32 -> bf16, grid-strided
  {
    size_t idx = ((size_t)(b * 256 + t)) * 8;
    const size_t stride = (size_t)GRID * 256 * 8;
    #pragma unroll
    for (int i = 0; i < 16; ++i, idx += stride) {
      floatx4 a = *reinterpret_cast<const floatx4*>(x + idx);
      floatx4 c = *reinterpret_cast<const floatx4*>(x + idx + 4);
      shortx8 o;
      o[0] = (short)f32_to_bf16_rne(a[0]); o[1] = (short)f32_to_bf16_rne(a[1]);
      o[2] = (short)f32_to_bf16_rne(a[2]); o[3] = (short)f32_to_bf16_rne(a[3]);
      o[4] = (short)f32_to_bf16_rne(c[0]); o[5] = (short)f32_to_bf16_rne(c[1]);
      o[6] = (short)f32_to_bf16_rne(c[2]); o[7] = (short)f32_to_bf16_rne(c[3]);
      *reinterpret_cast<shortx8*>(xb + idx) = o;
    }
  }
  // (b) transpose Wp|Ws -> Bt1 bf16 [2048][4096]; 4 virtual 64x64 tiles/block
  {
    ushort* tile = lA;                               // [64][72] alias
    #pragma unroll 1
    for (int i = 0; i < 4; ++i) {
      const int vt = b * 4 + i;                      // 0..2047
      const int z = vt >> 10, rest = vt & 1023;
      const int nt = rest >> 6, kt = rest & 63;
      const float* W = z ? Ws : Wp;
      __syncthreads();                               // WAR on tile reuse
      const int r = t >> 4, c = (t & 15) * 4;
      #pragma unroll
      for (int j = 0; j < 4; ++j) {
        const int kk = r + j * 16;
        floatx4 v = *reinterpret_cast<const floatx4*>(
            W + (size_t)(kt * 64 + kk) * 1024 + nt * 64 + c);
        tile[(c + 0) * 72 + kk] = f32_to_bf16_rne(v[0]);
        tile[(c + 1) * 72 + kk] = f32_to_bf16_rne(v[1]);
        tile[(c + 2) * 72 + kk] = f32_to_bf16_rne(v[2]);
        tile[(c + 3) * 72 + kk] = f32_to_bf16_rne(v[3]);
      }
      __syncthreads();
      const int nl = t >> 3, ch = t & 7;
      #pragma unroll
      for (int j = 0; j < 2; ++j) {
        const int n = nl + j * 32;
        shortx8 v = *reinterpret_cast<const shortx8*>(tile + n * 72 + ch * 8);
        *reinterpret_cast<shortx8*>(
            Bt1 + (size_t)(z * 1024 + nt * 64 + n) * 4096 + kt * 64 + ch * 8) = v;
      }
    }
  }
  // (c) pack cwb [32][128][1024] (rows: 32 cw0 | 64 cw1 | 32 zero) and
  //     Wcb [128][1024] (32 rows Wc^T | 96 zero)
  #pragma unroll 1
  for (int i = 0; i < 9; ++i) {
    const int row = b + GRID * i;
    if (row >= 4224) break;
    const int k = t * 4;
    float v0 = 0.f, v1 = 0.f, v2 = 0.f, v3 = 0.f;
    ushort* dst;
    if (row < 4096) {
      const int c = row >> 7, n = row & 127;
      if (n < 32) {
        floatx4 f = *reinterpret_cast<const floatx4*>(cw0 + (size_t)(c * 32 + n) * 1024 + k);
        v0 = f[0]; v1 = f[1]; v2 = f[2]; v3 = f[3];
      } else if (n < 96) {
        floatx4 f = *reinterpret_cast<const floatx4*>(cw1 + (size_t)(c * 64 + (n - 32)) * 1024 + k);
        v0 = f[0]; v1 = f[1]; v2 = f[2]; v3 = f[3];
      }
      dst = cwb + (size_t)row * 1024 + k;
    } else {
      const int n = row - 4096;
      if (n < 32) {
        v0 = Wc[(k + 0) * 32 + n]; v1 = Wc[(k + 1) * 32 + n];
        v2 = Wc[(k + 2) * 32 + n]; v3 = Wc[(k + 3) * 32 + n];
      }
      dst = Wcb + (size_t)n * 1024 + k;
    }
    shortx4 o;
    o[0] = (short)f32_to_bf16_rne(v0); o[1] = (short)f32_to_bf16_rne(v1);
    o[2] = (short)f32_to_bf16_rne(v2); o[3] = (short)f32_to_bf16_rne(v3);
    *reinterpret_cast<shortx4*>(dst) = o;
  }
  // (d) counting sort of y on block 0 (intra-class order irrelevant)
  if (b == 0) {
    if (t < 32) { hist[t] = 0; hcur[t] = 0; }
    __syncthreads();
    int yv[16];
    #pragma unroll
    for (int i = 0; i < 16; ++i) { yv[i] = y[t * 16 + i]; atomicAdd(&hist[yv[i]], 1); }
    __syncthreads();
    if (t == 0) {
      int s = 0;
      for (int c = 0; c < 32; ++c) { hbase[c] = s; offs[c] = s; s += hist[c]; }
      offs[32] = s;
    }
    __syncthreads();
    #pragma unroll
    for (int i = 0; i < 16; ++i) {
      const int c = yv[i];
      const int p = atomicAdd(&hcur[c], 1);
      perm[hbase[c] + p] = t * 16 + i;
    }
  }

  grid_barrier(bar, 0);

  // ====================== P1: gemm1 ======================
  {
    const int bx = b & 31, by = b >> 5;   // (m tile, n tile) of [32,16]
    floatx4 acc[4][4];
    const floatx4 z4 = {0.f, 0.f, 0.f, 0.f};
    #pragma unroll
    for (int i = 0; i < 4; ++i)
      #pragma unroll
      for (int j = 0; j < 4; ++j) acc[i][j] = z4;

    gemm_core_128(xb, Bt1, 4096, 4096, 4096, bx, by, lA, lB, acc);

    const int w = t >> 6, lane = t & 63;
    const int wr = w >> 1, wc = w & 1, r16 = lane & 15, quad = lane >> 4;
    const int sel = (by >= 8);
    const float* bias = sel ? bs : bp;
    float*  outF = sel ? S : P;
    ushort* outB = sel ? Sb : Pb;
    const int colbase = by * 128 - sel * 1024;
    #pragma unroll
    for (int mi = 0; mi < 4; ++mi) {
      #pragma unroll
      for (int ni = 0; ni < 4; ++ni) {
        const int n = colbase + wc * 64 + ni * 16 + r16;
        const float bv = bias[n];
        #pragma unroll
        for (int rg = 0; rg < 4; ++rg) {
          const int m = bx * 128 + wr * 64 + mi * 16 + quad * 4 + rg;
          const float v = acc[mi][ni][rg] + bv;
          const size_t off = (size_t)m * 1024 + n;
          outF[off] = v;
          outB[off] = f32_to_bf16_rne(v);
        }
      }
    }
  }

  grid_barrier(bar, 1);

  // ====================== P2: head ======================
  // virtual grid 32x33 via vb = vx*33 + vy (caps stacking at 2 gemms/block)
  #pragma unroll 1
  for (int i = 0; i < 3; ++i) {
    const int vb = b + GRID * i;
    if (vb >= 1056) break;
    const int vx = vb / 33;        // m-chunk 0..31
    const int vy = vb % 33;        // class 0..31, or 32 = parent

    const int w = t >> 6, lane = t & 63;
    const int wr = w >> 1, wc = w & 1, r16 = lane & 15, quad = lane >> 4;

    floatx4 acc[4][4];
    const floatx4 z4 = {0.f, 0.f, 0.f, 0.f};
    #pragma unroll
    for (int mi = 0; mi < 4; ++mi)
      #pragma unroll
      for (int ni = 0; ni < 4; ++ni) acc[mi][ni] = z4;

    if (vy == 32) {                // ---- parent logits ----
      gemm_core_128(Pb, Wcb, 1024, 1024, 1024, vx, 0, lA, lB, acc);
      if (wc == 0) {
        #pragma unroll
        for (int mi = 0; mi < 4; ++mi)
          #pragma unroll
          for (int ni = 0; ni < 2; ++ni) {
            const int n = ni * 16 + r16;
            const float bv = bc[n];
            #pragma unroll
            for (int rg = 0; rg < 4; ++rg) {
              const int m = vx * 128 + wr * 64 + mi * 16 + quad * 4 + rg;
              outParent[(size_t)m * 32 + n] = acc[mi][ni][rg] + bv;
            }
          }
      }
      continue;
    }

    // ---- child logits for class vy ----
    const int c    = vy;
    const int off0 = offs[c];
    const int cnt  = offs[c + 1] - off0;
    const int m0   = vx * BM;
    if (m0 >= cnt) continue;       // block-uniform skip

    const int sr = lane >> 3;
    const int sc = lane & 7;
    int rowSamp[4];
    #pragma unroll
    for (int c2 = 0; c2 < 4; ++c2) {
      const int r = 32 * w + 8 * c2 + sr;
      rowSamp[c2] = perm[off0 + min(m0 + r, cnt - 1)];
    }
    const ushort* Bbase = cwb + (size_t)c * 128 * 1024;

    for (int k0 = 0; k0 < 1024; k0 += BK) {
      #pragma unroll
      for (int c2 = 0; c2 < 4; ++c2) {
        const int r  = 32 * w + 8 * c2 + sr;
        const int gc = sc ^ sr;
        async_copy16(Sb + (size_t)rowSamp[c2] * 1024 + k0 + gc * 8,
                     lA + (32 * w + 8 * c2) * BK);
        async_copy16(Bbase + (size_t)r * 1024 + k0 + gc * 8,
                     lB + (32 * w + 8 * c2) * BK);
      }
      __syncthreads();
      mfma_bk_step(lA, lB, acc, wr, wc, r16, quad);
      __syncthreads();
    }

    #pragma unroll
    for (int mi = 0; mi < 4; ++mi) {
      #pragma unroll
      for (int rg = 0; rg < 4; ++rg) {
        const int gm = m0 + wr * 64 + mi * 16 + quad * 4 + rg;
        if (gm >= cnt) continue;
        const int sample = perm[off0 + gm];
        #pragma unroll
        for (int ni = 0; ni < 4; ++ni) {
          const int n = wc * 64 + ni * 16 + r16;
          if (n < 32)
            out0[(size_t)sample * 32 + n] = acc[mi][ni][rg] + cb0[c * 32 + n];
          else if (n < 96)
            out1[(size_t)sample * 64 + (n - 32)] = acc[mi][ni][rg] + cb1[c * 64 + (n - 32)];
        }
      }
    }
  }
}

// ---------------------------------------------------------------------------

extern "C" void kernel_launch(void* const* d_in, const int* in_sizes, int n_in,
                              void* d_out, int out_size, void* d_ws, size_t ws_size,
                              hipStream_t stream) {
  const float* x   = (const float*)d_in[0];
  const int*   y   = (const int*)  d_in[1];
  const float* Wp  = (const float*)d_in[2];
  const float* bp  = (const float*)d_in[3];
  const float* Ws  = (const float*)d_in[4];
  const float* bs  = (const float*)d_in[5];
  const float* Wc  = (const float*)d_in[6];
  const float* bc  = (const float*)d_in[7];
  const float* cw0 = (const float*)d_in[8];
  const float* cb0 = (const float*)d_in[9];
  const float* cw1 = (const float*)d_in[10];
  const float* cb1 = (const float*)d_in[11];

  float* out = (float*)d_out;
  float* parent_logits = out;               // [4096,32]
  float* child0        = out + 131072;      // [4096,32]
  float* child1        = out + 262144;      // [4096,64]
  float* P             = out + 524288;      // [4096,1024]
  float* S             = out + 4718592;     // [4096,1024]

  char* ws = (char*)d_ws;
  ushort* xb   = (ushort*)(ws);                  // 32 MB   [4096][4096]
  ushort* Bt1  = (ushort*)(ws + 33554432);       // 16 MB   [2048][4096]
  ushort* Pb   = (ushort*)(ws + 50331648);       // 8 MB    [4096][1024]
  ushort* Sb   = (ushort*)(ws + 58720256);       // 8 MB    [4096][1024]
  ushort* cwb  = (ushort*)(ws + 67108864);       // 8 MB    [32][128][1024]
  ushort* Wcb  = (ushort*)(ws + 75497472);       // 256 KB  [128][1024]
  int*    perm = (int*)   (ws + 75759616);       // 16 KB
  int*    offs = (int*)   (ws + 75776000);       // 132 B
  int*    bar  = (int*)   (ws + 75776192);       // 64 B barrier counters

  hipMemsetAsync(bar, 0, 64, stream);            // ws is poisoned 0xAA each launch
  k_mega<<<GRID, 256, 0, stream>>>(x, y, Wp, bp, Ws, bs, Wc, bc,
                                   cw0, cb0, cw1, cb1,
                                   xb, Bt1, Pb, Sb, cwb, Wcb,
                                   perm, offs, bar,
                                   P, S, parent_logits, child0, child1);
}

// Round 4
// 299.501 us; speedup vs baseline: 1.7931x; 1.7931x over previous
//
#include <hip/hip_runtime.h>
#include <hip/hip_bf16.h>
#include <stdint.h>

// ---------------------------------------------------------------------------
// JointEmbeddingClassifier on MI355X (gfx950) — R4.
// R3 post-mortem: persistent mega-kernel FAILED (429us; MFMA-busy time
// identical to R2 -> 300us of added stall from phase serialization at 2
// blocks/CU + device-fence cache kills). Reverted to multi-kernel.
// R4: (1) all independent prep fused into ONE launch (disjoint block ranges,
//     full occupancy, no barriers); (2) gemm1 BK=128 (64KB LDS) — halves
//     barrier-drain count; occupancy already grid-limited to 2 blocks/CU so
//     the m132 occupancy penalty does not apply here.
// ---------------------------------------------------------------------------

typedef __attribute__((ext_vector_type(4))) float  floatx4;
typedef __attribute__((ext_vector_type(8))) short  shortx8;
typedef __attribute__((ext_vector_type(4))) short  shortx4;
typedef __attribute__((ext_vector_type(8))) __bf16 bf16x8;

static __device__ __forceinline__ ushort f32_to_bf16_rne(float f) {
  uint32_t u = __builtin_bit_cast(uint32_t, f);
  u += 0x7FFFu + ((u >> 16) & 1u);      // RNE (no NaN inputs here)
  return (ushort)(u >> 16);
}

// async global->LDS, 16B per lane. LDS dest = wave-uniform base + lane*16;
// global address may be fully per-lane (used for perm-indirected rows).
static __device__ __forceinline__ void async_copy16(const void* g, void* lds) {
  __builtin_amdgcn_global_load_lds(
      (__attribute__((address_space(1))) void*)(uintptr_t)g,
      (__attribute__((address_space(3))) void*)(uintptr_t)lds,
      16, 0, 0);
}

// ======================= fused prep (one launch) ===========================
// blocks [0]            : counting sort of y -> perm, offs
// blocks [1, 4224]      : pack cwb [32][128][1024] + Wcb [128][1024]
// blocks [4225, 6272]   : transpose Wp|Ws -> Bt1 bf16 [2048][4096]
// blocks [6273, 14464]  : cast x f32 -> bf16
__global__ __launch_bounds__(256) void k_prep(
    const float* __restrict__ x,   const int* __restrict__ y,
    const float* __restrict__ Wp,  const float* __restrict__ Ws,
    const float* __restrict__ Wc,
    const float* __restrict__ cw0, const float* __restrict__ cw1,
    ushort* __restrict__ xb,  ushort* __restrict__ Bt1,
    ushort* __restrict__ cwb, ushort* __restrict__ Wcb,
    int* __restrict__ perm, int* __restrict__ offs)
{
  __shared__ __align__(16) ushort tile[64 * 72];
  __shared__ int hist[32], hbase[32], hcur[32];
  const int b = blockIdx.x;
  const int t = threadIdx.x;

  if (b == 0) {
    // ---- bucket: counting sort by class (intra-class order irrelevant) ----
    if (t < 32) { hist[t] = 0; hcur[t] = 0; }
    __syncthreads();
    int yv[16];
    #pragma unroll
    for (int i = 0; i < 16; ++i) { yv[i] = y[t * 16 + i]; atomicAdd(&hist[yv[i]], 1); }
    __syncthreads();
    if (t == 0) {
      int s = 0;
      for (int c = 0; c < 32; ++c) { hbase[c] = s; offs[c] = s; s += hist[c]; }
      offs[32] = s;
    }
    __syncthreads();
    #pragma unroll
    for (int i = 0; i < 16; ++i) {
      const int c = yv[i];
      const int p = atomicAdd(&hcur[c], 1);
      perm[hbase[c] + p] = t * 16 + i;
    }
  } else if (b <= 4224) {
    // ---- pack cwb (rows: 32 cw0 | 64 cw1 | 32 zero per class) + Wcb ----
    const int row = b - 1;               // 0..4223
    const int k = t * 4;
    float v0 = 0.f, v1 = 0.f, v2 = 0.f, v3 = 0.f;
    ushort* dst;
    if (row < 4096) {
      const int c = row >> 7, n = row & 127;
      if (n < 32) {
        floatx4 f = *reinterpret_cast<const floatx4*>(cw0 + (size_t)(c * 32 + n) * 1024 + k);
        v0 = f[0]; v1 = f[1]; v2 = f[2]; v3 = f[3];
      } else if (n < 96) {
        floatx4 f = *reinterpret_cast<const floatx4*>(cw1 + (size_t)(c * 64 + (n - 32)) * 1024 + k);
        v0 = f[0]; v1 = f[1]; v2 = f[2]; v3 = f[3];
      }
      dst = cwb + (size_t)row * 1024 + k;
    } else {
      const int n = row - 4096;          // 0..127
      if (n < 32) {
        v0 = Wc[(k + 0) * 32 + n]; v1 = Wc[(k + 1) * 32 + n];
        v2 = Wc[(k + 2) * 32 + n]; v3 = Wc[(k + 3) * 32 + n];
      }
      dst = Wcb + (size_t)n * 1024 + k;
    }
    shortx4 o;
    o[0] = (short)f32_to_bf16_rne(v0); o[1] = (short)f32_to_bf16_rne(v1);
    o[2] = (short)f32_to_bf16_rne(v2); o[3] = (short)f32_to_bf16_rne(v3);
    *reinterpret_cast<shortx4*>(dst) = o;
  } else if (b <= 6272) {
    // ---- transpose one 64x64 tile of Wp|Ws into Bt1 (K-contiguous) ----
    const int vt = b - 4225;             // 0..2047
    const int z = vt >> 10, rest = vt & 1023;
    const int nt = rest >> 6, kt = rest & 63;
    const float* W = z ? Ws : Wp;
    const int r = t >> 4, c = (t & 15) * 4;
    #pragma unroll
    for (int j = 0; j < 4; ++j) {
      const int kk = r + j * 16;
      floatx4 v = *reinterpret_cast<const floatx4*>(
          W + (size_t)(kt * 64 + kk) * 1024 + nt * 64 + c);
      tile[(c + 0) * 72 + kk] = f32_to_bf16_rne(v[0]);
      tile[(c + 1) * 72 + kk] = f32_to_bf16_rne(v[1]);
      tile[(c + 2) * 72 + kk] = f32_to_bf16_rne(v[2]);
      tile[(c + 3) * 72 + kk] = f32_to_bf16_rne(v[3]);
    }
    __syncthreads();
    const int nl = t >> 3, ch = t & 7;
    #pragma unroll
    for (int j = 0; j < 2; ++j) {
      const int n = nl + j * 32;
      shortx8 v = *reinterpret_cast<const shortx8*>(tile + n * 72 + ch * 8);
      *reinterpret_cast<shortx8*>(
          Bt1 + (size_t)(z * 1024 + nt * 64 + n) * 4096 + kt * 64 + ch * 8) = v;
    }
  } else {
    // ---- cast x -> bf16 ----
    const size_t i = ((size_t)(b - 6273) * 256 + t) * 8;
    floatx4 a = *reinterpret_cast<const floatx4*>(x + i);
    floatx4 c = *reinterpret_cast<const floatx4*>(x + i + 4);
    shortx8 o;
    o[0] = (short)f32_to_bf16_rne(a[0]); o[1] = (short)f32_to_bf16_rne(a[1]);
    o[2] = (short)f32_to_bf16_rne(a[2]); o[3] = (short)f32_to_bf16_rne(a[3]);
    o[4] = (short)f32_to_bf16_rne(c[0]); o[5] = (short)f32_to_bf16_rne(c[1]);
    o[6] = (short)f32_to_bf16_rne(c[2]); o[7] = (short)f32_to_bf16_rne(c[3]);
    *reinterpret_cast<shortx8*>(xb + i) = o;
  }
}

// ======================= gemm1: BK=128 =====================================
// C[4096,2048] = xb . Bt1^T ; cols 0..1023 -> P (+bp), 1024..2047 -> S (+bs).
// LDS 2x32KB, physical 16B-chunk = logical ^ (row&15) swizzle.
__global__ __launch_bounds__(256) void k_gemm1(
    const ushort* __restrict__ xb, const ushort* __restrict__ Bt1,
    const float* __restrict__ bp, const float* __restrict__ bs,
    float* __restrict__ outP, float* __restrict__ outS,
    ushort* __restrict__ Pb, ushort* __restrict__ Sb)
{
  __shared__ __align__(16) ushort lA[128 * 128];   // 32 KB
  __shared__ __align__(16) ushort lB[128 * 128];   // 32 KB
  floatx4 acc[4][4];
  const floatx4 z4 = {0.f, 0.f, 0.f, 0.f};
  #pragma unroll
  for (int i = 0; i < 4; ++i)
    #pragma unroll
    for (int j = 0; j < 4; ++j) acc[i][j] = z4;

  const int t    = threadIdx.x;
  const int w    = t >> 6;
  const int lane = t & 63;
  const int wr   = w >> 1;
  const int wc   = w & 1;
  const int r16  = lane & 15;
  const int quad = lane >> 4;
  const int sr4  = lane >> 4;   // staging: row within 4-row group
  const int sc16 = lane & 15;   // staging: 16B chunk slot (16 per 256B row)

  const ushort* Abase = xb  + (size_t)(blockIdx.x * 128) * 4096;
  const ushort* Bbase = Bt1 + (size_t)(blockIdx.y * 128) * 4096;

  for (int k0 = 0; k0 < 4096; k0 += 128) {
    // stage A & B 128x128 tiles: wave w covers rows 32w..32w+31, 8 calls each
    #pragma unroll
    for (int c2 = 0; c2 < 8; ++c2) {
      const int r  = 32 * w + 4 * c2 + sr4;
      const int gc = sc16 ^ (r & 15);
      async_copy16(Abase + (size_t)r * 4096 + k0 + gc * 8, lA + (32 * w + 4 * c2) * 128);
      async_copy16(Bbase + (size_t)r * 4096 + k0 + gc * 8, lB + (32 * w + 4 * c2) * 128);
    }
    __syncthreads();
    #pragma unroll
    for (int ks = 0; ks < 4; ++ks) {
      bf16x8 af[4], bfv[4];
      const int pc = (((ks * 4) + quad) ^ r16) * 8;   // physical chunk (ushorts)
      #pragma unroll
      for (int mi = 0; mi < 4; ++mi)
        af[mi] = *reinterpret_cast<const bf16x8*>(lA + (wr * 64 + mi * 16 + r16) * 128 + pc);
      #pragma unroll
      for (int ni = 0; ni < 4; ++ni)
        bfv[ni] = *reinterpret_cast<const bf16x8*>(lB + (wc * 64 + ni * 16 + r16) * 128 + pc);
      #pragma unroll
      for (int mi = 0; mi < 4; ++mi)
        #pragma unroll
        for (int ni = 0; ni < 4; ++ni)
          acc[mi][ni] = __builtin_amdgcn_mfma_f32_16x16x32_bf16(
              af[mi], bfv[ni], acc[mi][ni], 0, 0, 0);
    }
    __syncthreads();
  }

  const int sel = (blockIdx.y >= 8);
  const float* bias = sel ? bs : bp;
  float*  outF = sel ? outS : outP;
  ushort* outB = sel ? Sb : Pb;
  const int colbase = blockIdx.y * 128 - sel * 1024;
  #pragma unroll
  for (int mi = 0; mi < 4; ++mi) {
    #pragma unroll
    for (int ni = 0; ni < 4; ++ni) {
      const int n = colbase + wc * 64 + ni * 16 + r16;
      const float bv = bias[n];
      #pragma unroll
      for (int rg = 0; rg < 4; ++rg) {
        const int m = blockIdx.x * 128 + wr * 64 + mi * 16 + quad * 4 + rg;
        const float v = acc[mi][ni][rg] + bv;
        const size_t off = (size_t)m * 1024 + n;
        outF[off] = v;
        outB[off] = f32_to_bf16_rne(v);
      }
    }
  }
}

// ======================= head (BK=64, as R2) ===============================
static __device__ __forceinline__ void mfma_bk_step64(
    const ushort* lA, const ushort* lB, floatx4 acc[4][4],
    int wr, int wc, int r16, int quad)
{
  #pragma unroll
  for (int ks = 0; ks < 2; ++ks) {
    bf16x8 af[4], bfv[4];
    const int pc = (((ks * 4) + quad) ^ (r16 & 7)) * 8;
    #pragma unroll
    for (int mi = 0; mi < 4; ++mi)
      af[mi] = *reinterpret_cast<const bf16x8*>(lA + (wr * 64 + mi * 16 + r16) * 64 + pc);
    #pragma unroll
    for (int ni = 0; ni < 4; ++ni)
      bfv[ni] = *reinterpret_cast<const bf16x8*>(lB + (wc * 64 + ni * 16 + r16) * 64 + pc);
    #pragma unroll
    for (int mi = 0; mi < 4; ++mi)
      #pragma unroll
      for (int ni = 0; ni < 4; ++ni)
        acc[mi][ni] = __builtin_amdgcn_mfma_f32_16x16x32_bf16(
            af[mi], bfv[ni], acc[mi][ni], 0, 0, 0);
  }
}

// blockIdx.y==32: parent logits (A=Pb, B=Wcb). blockIdx.y==c<32: child logits
// for class c — A rows gathered via perm, B=cwb[c]; cols 0..31->child0,
// 32..95->child1.
__global__ __launch_bounds__(256) void k_head(
    const ushort* __restrict__ Sb, const ushort* __restrict__ Pb,
    const ushort* __restrict__ cwb, const ushort* __restrict__ Wcb,
    const int* __restrict__ perm, const int* __restrict__ off,
    const float* __restrict__ cb0, const float* __restrict__ cb1,
    const float* __restrict__ bc,
    float* __restrict__ out0, float* __restrict__ out1,
    float* __restrict__ outParent)
{
  __shared__ __align__(16) ushort lA[128 * 64];
  __shared__ __align__(16) ushort lB[128 * 64];
  floatx4 acc[4][4];
  const floatx4 z4 = {0.f, 0.f, 0.f, 0.f};
  #pragma unroll
  for (int i = 0; i < 4; ++i)
    #pragma unroll
    for (int j = 0; j < 4; ++j) acc[i][j] = z4;

  const int t = threadIdx.x, w = t >> 6, lane = t & 63;
  const int wr = w >> 1, wc = w & 1, r16 = lane & 15, quad = lane >> 4;
  const int sr = lane >> 3, sc = lane & 7;

  if (blockIdx.y == 32) {                       // ---- parent logits ----
    const ushort* Abase = Pb + (size_t)(blockIdx.x * 128) * 1024;
    for (int k0 = 0; k0 < 1024; k0 += 64) {
      #pragma unroll
      for (int c2 = 0; c2 < 4; ++c2) {
        const int r  = 32 * w + 8 * c2 + sr;
        const int gc = sc ^ sr;
        async_copy16(Abase + (size_t)r * 1024 + k0 + gc * 8, lA + (32 * w + 8 * c2) * 64);
        async_copy16(Wcb   + (size_t)r * 1024 + k0 + gc * 8, lB + (32 * w + 8 * c2) * 64);
      }
      __syncthreads();
      mfma_bk_step64(lA, lB, acc, wr, wc, r16, quad);
      __syncthreads();
    }
    if (wc == 0) {
      #pragma unroll
      for (int mi = 0; mi < 4; ++mi)
        #pragma unroll
        for (int ni = 0; ni < 2; ++ni) {
          const int n = ni * 16 + r16;
          const float bv = bc[n];
          #pragma unroll
          for (int rg = 0; rg < 4; ++rg) {
            const int m = blockIdx.x * 128 + wr * 64 + mi * 16 + quad * 4 + rg;
            outParent[(size_t)m * 32 + n] = acc[mi][ni][rg] + bv;
          }
        }
    }
    return;
  }

  // ---- child logits for class c ----
  const int c    = blockIdx.y;
  const int off0 = off[c];
  const int cnt  = off[c + 1] - off0;
  const int m0   = blockIdx.x * 128;
  if (m0 >= cnt) return;                        // block-uniform exit

  int rowSamp[4];
  #pragma unroll
  for (int c2 = 0; c2 < 4; ++c2) {
    const int r = 32 * w + 8 * c2 + sr;
    rowSamp[c2] = perm[off0 + min(m0 + r, cnt - 1)];
  }
  const ushort* Bbase = cwb + (size_t)c * 128 * 1024;

  for (int k0 = 0; k0 < 1024; k0 += 64) {
    #pragma unroll
    for (int c2 = 0; c2 < 4; ++c2) {
      const int r  = 32 * w + 8 * c2 + sr;
      const int gc = sc ^ sr;
      async_copy16(Sb + (size_t)rowSamp[c2] * 1024 + k0 + gc * 8, lA + (32 * w + 8 * c2) * 64);
      async_copy16(Bbase + (size_t)r * 1024 + k0 + gc * 8,        lB + (32 * w + 8 * c2) * 64);
    }
    __syncthreads();
    mfma_bk_step64(lA, lB, acc, wr, wc, r16, quad);
    __syncthreads();
  }

  #pragma unroll
  for (int mi = 0; mi < 4; ++mi) {
    #pragma unroll
    for (int rg = 0; rg < 4; ++rg) {
      const int gm = m0 + wr * 64 + mi * 16 + quad * 4 + rg;
      if (gm >= cnt) continue;
      const int sample = perm[off0 + gm];
      #pragma unroll
      for (int ni = 0; ni < 4; ++ni) {
        const int n = wc * 64 + ni * 16 + r16;
        if (n < 32)
          out0[(size_t)sample * 32 + n] = acc[mi][ni][rg] + cb0[c * 32 + n];
        else if (n < 96)
          out1[(size_t)sample * 64 + (n - 32)] = acc[mi][ni][rg] + cb1[c * 64 + (n - 32)];
      }
    }
  }
}

// ---------------------------------------------------------------------------

extern "C" void kernel_launch(void* const* d_in, const int* in_sizes, int n_in,
                              void* d_out, int out_size, void* d_ws, size_t ws_size,
                              hipStream_t stream) {
  const float* x   = (const float*)d_in[0];
  const int*   y   = (const int*)  d_in[1];
  const float* Wp  = (const float*)d_in[2];
  const float* bp  = (const float*)d_in[3];
  const float* Ws  = (const float*)d_in[4];
  const float* bs  = (const float*)d_in[5];
  const float* Wc  = (const float*)d_in[6];
  const float* bc  = (const float*)d_in[7];
  const float* cw0 = (const float*)d_in[8];
  const float* cb0 = (const float*)d_in[9];
  const float* cw1 = (const float*)d_in[10];
  const float* cb1 = (const float*)d_in[11];

  float* out = (float*)d_out;
  float* parent_logits = out;               // [4096,32]
  float* child0        = out + 131072;      // [4096,32]
  float* child1        = out + 262144;      // [4096,64]
  float* P             = out + 524288;      // [4096,1024]
  float* S             = out + 4718592;     // [4096,1024]

  char* ws = (char*)d_ws;
  ushort* xb   = (ushort*)(ws);                  // 32 MB   [4096][4096]
  ushort* Bt1  = (ushort*)(ws + 33554432);       // 16 MB   [2048][4096]
  ushort* Pb   = (ushort*)(ws + 50331648);       // 8 MB    [4096][1024]
  ushort* Sb   = (ushort*)(ws + 58720256);       // 8 MB    [4096][1024]
  ushort* cwb  = (ushort*)(ws + 67108864);       // 8 MB    [32][128][1024]
  ushort* Wcb  = (ushort*)(ws + 75497472);       // 256 KB  [128][1024]
  int*    perm = (int*)   (ws + 75759616);       // 16 KB
  int*    offs = (int*)   (ws + 75776000);       // 132 B

  k_prep <<<14465, 256, 0, stream>>>(x, y, Wp, Ws, Wc, cw0, cw1,
                                     xb, Bt1, cwb, Wcb, perm, offs);
  k_gemm1<<<dim3(32, 16), 256, 0, stream>>>(xb, Bt1, bp, bs, P, S, Pb, Sb);
  k_head <<<dim3(32, 33), 256, 0, stream>>>(Sb, Pb, cwb, Wcb, perm, offs,
                                            cb0, cb1, bc,
                                            child0, child1, parent_logits);
}